// Round 1
// 112.546 us; speedup vs baseline: 1.0112x; 1.0112x over previous
//
#include <hip/hip_runtime.h>
#include <math.h>

#define OUT 260
#define TAPS 6
#define IMG_H 2048
#define IMG_W 2048
#define ROW_F (IMG_W * 3)            // 6144 floats per image row
#define NB 10
#define TH 0.8f
#define LDSF 6152                    // worst span: 3*2048 + align slop
#define NXCD 8
#define NWG (NB * OUT)               // 2600 blocks; 2600 % 8 == 0 -> clean swizzle
#define CPX (NWG / NXCD)             // 325 blocks per XCD chunk

__device__ __forceinline__ float sincf(float x) {
    if (x == 0.0f) return 1.0f;
    float px = 3.14159265358979323846f * x;
    return __sinf(px) / px;
}

// One block per (p, box): stage the full 6-row x-span with the vertical
// 6-tap combine folded into registers (one fp32 row lands in LDS), then
// each lane produces one output pixel via the horizontal 6-tap.
// Horizontal weights are computed per-lane in registers BEFORE the staging
// loop so the sincf VALU work overlaps the in-flight global loads.
__global__ __launch_bounds__(256) void crop_resize_one(
    const float* __restrict__ scores, const float* __restrict__ boxes,
    const float* __restrict__ img, float* __restrict__ out)
{
    // XCD-aware bijective swizzle: original bid round-robins XCDs (bid % 8);
    // remap so each XCD owns a contiguous (box, p) chunk -> consecutive p
    // blocks share 1.7-5 of their 6 input rows in the same L2.
    const int bid  = blockIdx.x;
    const int lbid = (bid & (NXCD - 1)) * CPX + (bid >> 3);
    const int p    = lbid % OUT;
    const int box  = lbid / OUT;

    const float b0 = boxes[box * 4 + 0];
    const float b1 = boxes[box * 4 + 1];
    const float b2 = boxes[box * 4 + 2];
    const float b3 = boxes[box * 4 + 3];
    const int y0 = (int)(b0 * (float)IMG_H);
    const int x0 = (int)(b1 * (float)IMG_W);
    const int y1 = (int)(b2 * (float)IMG_H);
    const int x1 = (int)(b3 * (float)IMG_W);
    const int ch = max(y1 - y0, 1);
    const int cw = max(x1 - x0, 1);
    const bool valid = (scores[0] >= TH) && (scores[box] >= TH)
                    && (b1 >= 0.0f) && (b3 <= 1.0f);
    const float vmask = valid ? 1.0f : 0.0f;

    // ---- vertical taps (block-uniform; computed redundantly per lane) ----
    float wh[TAPS]; int ih[TAPS];
    {
        const float src = ((float)p + 0.5f) * ((float)ch / (float)OUT) - 0.5f;
        const int base = (int)floorf(src) - 2;
        float s = 0.0f;
        #pragma unroll
        for (int k = 0; k < TAPS; ++k) {
            const float d = src - (float)(base + k);
            const float w = (fabsf(d) < 3.0f) ? sincf(d) * sincf(d * (1.0f / 3.0f)) : 0.0f;
            wh[k] = w; s += w;
            int t = base + k; t = t < 0 ? 0 : t; t = t > ch - 1 ? ch - 1 : t;
            ih[k] = t + y0;
        }
        const float inv = 1.0f / s;
        #pragma unroll
        for (int k = 0; k < TAPS; ++k) wh[k] *= inv;
    }

    const int start_f = (x0 * 3) & ~3;
    const int n_f     = (x0 + cw) * 3 - start_f;   // <= 6147

    // ---- horizontal taps for q = tid (hoisted above staging) ----
    const int q = threadIdx.x;                      // 0..255, always < OUT
    const float wscale = (float)cw / (float)OUT;
    float ww[TAPS]; int lb[TAPS]; float hm;
    {
        const float src = ((float)q + 0.5f) * wscale - 0.5f;
        const int base = (int)floorf(src) - 2;
        float s = 0.0f;
        #pragma unroll
        for (int k = 0; k < TAPS; ++k) {
            const float d = src - (float)(base + k);
            const float w = (fabsf(d) < 3.0f) ? sincf(d) * sincf(d * (1.0f / 3.0f)) : 0.0f;
            ww[k] = w; s += w;
            int t = base + k; t = t < 0 ? 0 : t; t = t > cw - 1 ? cw - 1 : t;
            lb[k] = (x0 + t) * 3 - start_f;
        }
        hm = vmask / s;
    }

    // ---- stage: 6 rows, vertical combine in regs, one fp32 LDS row ----
    __shared__ float lds[LDSF];
    {
        const float* r0 = img + (size_t)ih[0] * ROW_F + start_f;
        const float* r1 = img + (size_t)ih[1] * ROW_F + start_f;
        const float* r2 = img + (size_t)ih[2] * ROW_F + start_f;
        const float* r3 = img + (size_t)ih[3] * ROW_F + start_f;
        const float* r4 = img + (size_t)ih[4] * ROW_F + start_f;
        const float* r5 = img + (size_t)ih[5] * ROW_F + start_f;
        for (int f = threadIdx.x * 4; f < n_f; f += 256 * 4) {
            const float4 v0 = *(const float4*)(r0 + f);
            const float4 v1 = *(const float4*)(r1 + f);
            const float4 v2 = *(const float4*)(r2 + f);
            const float4 v3 = *(const float4*)(r3 + f);
            const float4 v4 = *(const float4*)(r4 + f);
            const float4 v5 = *(const float4*)(r5 + f);
            float4 acc;
            acc.x = wh[0]*v0.x + wh[1]*v1.x + wh[2]*v2.x + wh[3]*v3.x + wh[4]*v4.x + wh[5]*v5.x;
            acc.y = wh[0]*v0.y + wh[1]*v1.y + wh[2]*v2.y + wh[3]*v3.y + wh[4]*v4.y + wh[5]*v5.y;
            acc.z = wh[0]*v0.z + wh[1]*v1.z + wh[2]*v2.z + wh[3]*v3.z + wh[4]*v4.z + wh[5]*v5.z;
            acc.w = wh[0]*v0.w + wh[1]*v1.w + wh[2]*v2.w + wh[3]*v3.w + wh[4]*v4.w + wh[5]*v5.w;
            *(float4*)(lds + f) = acc;
        }
    }
    __syncthreads();

    // ---- compute: one output pixel per lane ----
    {
        float a0 = 0.0f, a1 = 0.0f, a2 = 0.0f;
        #pragma unroll
        for (int k = 0; k < TAPS; ++k) {
            a0 = fmaf(ww[k], lds[lb[k] + 0], a0);
            a1 = fmaf(ww[k], lds[lb[k] + 1], a1);
            a2 = fmaf(ww[k], lds[lb[k] + 2], a2);
        }
        const size_t o = (((size_t)box * OUT + p) * OUT + q) * 3;
        out[o + 0] = a0 * hm;
        out[o + 1] = a1 * hm;
        out[o + 2] = a2 * hm;
    }

    // ---- tail: q = 256..259 handled by lanes 0..3 ----
    if (threadIdx.x < OUT - 256) {
        const int q2 = 256 + threadIdx.x;
        const float src = ((float)q2 + 0.5f) * wscale - 0.5f;
        const int base = (int)floorf(src) - 2;
        float w2[TAPS]; int l2i[TAPS]; float s = 0.0f;
        #pragma unroll
        for (int k = 0; k < TAPS; ++k) {
            const float d = src - (float)(base + k);
            const float w = (fabsf(d) < 3.0f) ? sincf(d) * sincf(d * (1.0f / 3.0f)) : 0.0f;
            w2[k] = w; s += w;
            int t = base + k; t = t < 0 ? 0 : t; t = t > cw - 1 ? cw - 1 : t;
            l2i[k] = (x0 + t) * 3 - start_f;
        }
        const float m2 = vmask / s;
        float a0 = 0.0f, a1 = 0.0f, a2 = 0.0f;
        #pragma unroll
        for (int k = 0; k < TAPS; ++k) {
            a0 = fmaf(w2[k], lds[l2i[k] + 0], a0);
            a1 = fmaf(w2[k], lds[l2i[k] + 1], a1);
            a2 = fmaf(w2[k], lds[l2i[k] + 2], a2);
        }
        const size_t o = (((size_t)box * OUT + p) * OUT + q2) * 3;
        out[o + 0] = a0 * m2;
        out[o + 1] = a1 * m2;
        out[o + 2] = a2 * m2;
    }
}

extern "C" void kernel_launch(void* const* d_in, const int* in_sizes, int n_in,
                              void* d_out, int out_size, void* d_ws, size_t ws_size,
                              hipStream_t stream) {
    const float* scores = (const float*)d_in[0];   // (100,)
    const float* boxes  = (const float*)d_in[1];   // (100,4)
    const float* img    = (const float*)d_in[2];   // (1,2048,2048,3)
    float* out = (float*)d_out;                    // (10,260,260,3)
    // Single kernel, no workspace: removes the tables launch + graph
    // dependency and 43 MB of table re-reads; weights are recomputed
    // per-lane in registers (aggregate ~2 us of VALU, hidden under loads).
    crop_resize_one<<<dim3(NWG), dim3(256), 0, stream>>>(scores, boxes, img, out);
}